// Round 19
// baseline (413.807 us; speedup 1.0000x reference)
//
#include <hip/hip_runtime.h>
#include <hip/hip_bf16.h>
#include <stdint.h>

typedef unsigned short ushort_t;
typedef __bf16 bf16x8 __attribute__((ext_vector_type(8)));
typedef float    f32x4 __attribute__((ext_vector_type(4)));
typedef float   f32x16 __attribute__((ext_vector_type(16)));
typedef unsigned short us4 __attribute__((ext_vector_type(4)));
typedef unsigned int ui4 __attribute__((ext_vector_type(4)));

#define QK_SCALE 0.12751744f   /* log2(e) / sqrt(128) : folded into Q so softmax uses exp2 */
#define NEG_BIG  -1e30f

#define BARRIER() do { asm volatile("" ::: "memory"); __builtin_amdgcn_s_barrier(); asm volatile("" ::: "memory"); } while (0)
#define VMCNT(N)  asm volatile("s_waitcnt vmcnt(" #N ")" ::: "memory")
#define MFMA16(d, a, b) d = __builtin_amdgcn_mfma_f32_16x16x32_bf16(a, b, d, 0, 0, 0)

__device__ __forceinline__ unsigned short f2bf(float f) {
    union { float f; unsigned int u; } v; v.f = f;
    unsigned int u = v.u;
    return (unsigned short)((u + 0x7FFFu + ((u >> 16) & 1u)) >> 16);  // RNE
}

// HW packed convert: dst.lo = bf16(a), dst.hi = bf16(b)
__device__ __forceinline__ unsigned int pk2bf(float a, float b) {
    unsigned int r;
    asm("v_cvt_pk_bf16_f32 %0, %1, %2" : "=v"(r) : "v"(a), "v"(b));
    return r;
}

// async global->LDS, 16B per lane. LDS dest is wave-uniform base + lane*16.
__device__ __forceinline__ void gload16(const void* g, void* l) {
    __builtin_amdgcn_global_load_lds(
        (__attribute__((address_space(1))) void*)(uintptr_t)g,
        (__attribute__((address_space(3))) void*)(uint32_t)(uintptr_t)l,
        16, 0, 0);
}

// ---------------- prep kernels ----------------

__global__ __launch_bounds__(256) void cvt_bf16_kernel(
    const float4* __restrict__ in, us4* __restrict__ out, int n4) {
    int i = blockIdx.x * 256 + threadIdx.x;
    if (i >= n4) return;
    float4 v = in[i];
    us4 o; o[0] = f2bf(v.x); o[1] = f2bf(v.y); o[2] = f2bf(v.z); o[3] = f2bf(v.w);
    out[i] = o;
}

// generic: in [R][C] fp32 -> out [C][R] bf16
__global__ __launch_bounds__(256) void transpose_bf16(
    const float* __restrict__ in, ushort_t* __restrict__ out, int R, int C) {
    __shared__ float t[64][65];
    int c0 = blockIdx.x * 64, r0 = blockIdx.y * 64;
    int cc = threadIdx.x & 63, rr = threadIdx.x >> 6;
#pragma unroll
    for (int i = 0; i < 16; ++i) {
        int r = i * 4 + rr;
        t[r][cc] = in[(size_t)(r0 + r) * C + c0 + cc];
    }
    __syncthreads();
#pragma unroll
    for (int i = 0; i < 16; ++i) {
        int r = i * 4 + rr;
        out[(size_t)(c0 + r) * R + r0 + cc] = f2bf(t[cc][r]);
    }
}

// Wqkv transpose with Q/K head-dim bit-permutation (R8-verified, QK^T-invariant)
__global__ __launch_bounds__(256) void transpose_wqkv(
    const float* __restrict__ in /*[2048][6144]*/, ushort_t* __restrict__ out /*[6144][2048]*/) {
    __shared__ float t[64][65];
    int c0 = blockIdx.x * 64, r0 = blockIdx.y * 64;
    int cc = threadIdx.x & 63, rr = threadIdx.x >> 6;
    int n = c0 + cc;
    int which = n >> 11;
    int src = n;
    if (which < 2) {
        int h = (n >> 7) & 15, p = n & 127;
        int po = (p & 15) | (((p >> 5) & 3) << 4) | (((p >> 4) & 1) << 6);
        src = (which << 11) + (h << 7) + po;
    }
#pragma unroll
    for (int i = 0; i < 16; ++i) {
        int r = i * 4 + rr;
        t[r][cc] = in[(size_t)(r0 + r) * 6144 + src];
    }
    __syncthreads();
#pragma unroll
    for (int i = 0; i < 16; ++i) {
        int r = i * 4 + rr;
        out[(size_t)(c0 + r) * 2048 + r0 + cc] = f2bf(t[cc][r]);
    }
}

// rope table: [L][64] of (cos, sin)
__global__ __launch_bounds__(256) void rope_table_kernel(float2* __restrict__ rope) {
    int i = blockIdx.x * 256 + threadIdx.x;     // L*64 = 131072 exactly
    int l = i >> 6, j = i & 63;
    float inv = exp2f((float)j * -0.20762050593046f);  // 10000^(-j/64)
    float f = (float)l * inv;
    rope[i] = make_float2(cosf(f), sinf(f));
}

// ---------------- 256x256 8-phase GEMM: single barrier/phase + widened A-ch0 windows ----
// R16 schedule with A-ch0 stages slid one phase earlier (buf1: P2->P1, buf0: P6->P5) so
// every chunk gets >=3 phases of flight before the vmcnt that demands it (was 2 for A-ch0,
// marginal vs ~900cyc HBM latency). Hazards re-verified: buf1.A-ch0 last read = P8 prev
// (A_lo re-read) -> stage P1 keeps 1-barrier gap; buf0.A-ch0 last read = P4 -> stage P5.
// vmcnt ledger: P4 outstanding = prevP7(2)+prevP8(2)+P1(4)+P3(2)+P4(2)=12, vmcnt(4)
// completes oldest 8 = all of buf1-'to'. P8 outstanding = P3+P4+P5+P7+P8 = 12, vmcnt(4)
// completes P3/P4/P5 = all of buf0-te+2.

template <int EPI>
__global__ __launch_bounds__(512, 2)
void gemm256(const ushort_t* __restrict__ A, const ushort_t* __restrict__ Bt,
             int M, int N, int K,
             float* __restrict__ C,
             ushort_t* __restrict__ Qb, ushort_t* __restrict__ Kb,
             ushort_t* __restrict__ Vt, const float2* __restrict__ rope) {
    __shared__ __attribute__((aligned(16))) char lds[131072];

    const int tid  = threadIdx.x;
    const int lane = tid & 63, wid = tid >> 6;
    const int lr = lane & 15, lg = lane >> 4;
    const int wr = wid >> 2, wc = wid & 3;        // wave grid 2(M) x 4(N)

    const int nbn = N >> 8;
    const int nwg = gridDim.x;
    const int bid = blockIdx.x;
    const int wg  = (bid & 7) * (nwg >> 3) + (bid >> 3);   // XCD-contiguous
    const int bm  = wg / nbn, bn = wg % nbn;

    const int srow = tid >> 3;                                   // 0..63
    const int scol = ((tid & 7) << 4) ^ ((srow & 7) << 4);
    const size_t rowK2 = (size_t)K * 2;
    const char* sA0 = (const char*)A + ((size_t)(bm * 256 + srow)) * rowK2 + scol;
    const char* sA1 = sA0 + 128 * rowK2;
    const char* sB0 = (const char*)Bt + ((size_t)(bn * 256 + srow)) * rowK2 + scol;
    const char* sB1 = sB0 + 128 * rowK2;

    auto stg = [&](const char* s, int ch, int kt, int dst) {
        gload16(s + (size_t)(ch * 64) * rowK2 + (size_t)kt * 128, lds + dst + wid * 1024);
    };

    const int xk0 = (lg * 16) ^ ((lr & 7) << 4);
    const int xk1 = (64 + lg * 16) ^ ((lr & 7) << 4);
    const int rowA = wr * 16384 + lr * 128;
    const int rowB = 32768 + (wc >> 1) * 16384 + ((wc & 1) * 64 + lr) * 128;

    auto rdA = [&](int bu, int mi, int kk) -> bf16x8 {
        return *(const bf16x8*)(lds + bu * 65536 + rowA + mi * 2048 + (kk ? xk1 : xk0));
    };
    auto rdB = [&](int bu, int ni, int kk) -> bf16x8 {
        return *(const bf16x8*)(lds + bu * 65536 + rowB + ni * 2048 + (kk ? xk1 : xk0));
    };

    f32x4 acc[8][4];
#pragma unroll
    for (int m = 0; m < 8; ++m)
#pragma unroll
        for (int n = 0; n < 4; ++n) acc[m][n] = (f32x4){0.f, 0.f, 0.f, 0.f};

    bf16x8 aF[4][2], bF[2][2];

#define RD_A(BU, MH) do { _Pragma("unroll") for (int mi = 0; mi < 4; ++mi) { \
        aF[mi][0] = rdA(BU, (MH)*4 + mi, 0); aF[mi][1] = rdA(BU, (MH)*4 + mi, 1); } } while (0)
#define RD_B(BU, NH) do { _Pragma("unroll") for (int ni = 0; ni < 2; ++ni) { \
        bF[ni][0] = rdB(BU, (NH)*2 + ni, 0); bF[ni][1] = rdB(BU, (NH)*2 + ni, 1); } } while (0)
#define QUAD(MH, NH) do { __builtin_amdgcn_s_setprio(1); \
        _Pragma("unroll") for (int kk = 0; kk < 2; ++kk) \
        _Pragma("unroll") for (int mi = 0; mi < 4; ++mi) \
        _Pragma("unroll") for (int ni = 0; ni < 2; ++ni) \
            MFMA16(acc[(MH)*4 + mi][(NH)*2 + ni], aF[mi][kk], bF[ni][kk]); \
        __builtin_amdgcn_s_setprio(0); } while (0)

    // ---- prologue: buf0 <- tile0 (8 chunks); buf1 <- tile1 {A0c1,A1c1,B0c0,B0c1} ----
    stg(sA0, 0, 0, 0);     stg(sA0, 1, 0, 8192);
    stg(sA1, 0, 0, 16384); stg(sA1, 1, 0, 24576);
    stg(sB0, 0, 0, 32768); stg(sB0, 1, 0, 40960);
    stg(sB1, 0, 0, 49152); stg(sB1, 1, 0, 57344);
    stg(sA0, 1, 1, 73728); stg(sA1, 1, 1, 90112);
    stg(sB0, 0, 1, 98304); stg(sB0, 1, 1, 106496);
    VMCNT(4);
    BARRIER();

    const int NIT = K / 128;
    for (int i = 0; i < NIT; ++i) {
        const int to = 2 * i + 1, te2 = 2 * i + 2, to2 = 2 * i + 3;
        const bool g = (i + 1 < NIT);

        // P1: stage buf1.B1(to) + buf1.A-ch0(to)  [A-ch0 moved from P2: 3-phase window]
        RD_A(0, 0); RD_B(0, 0);
        stg(sB1, 0, to, 114688); stg(sB1, 1, to, 122880);
        stg(sA0, 0, to, 65536);  stg(sA1, 0, to, 81920);
        QUAD(0, 0); BARRIER();

        // P2: no stages (pure compute)
        RD_A(0, 1);
        QUAD(1, 0); BARRIER();

        // P3: stage buf0.A-ch1 (te+2)
        RD_B(0, 1);
        if (g) { stg(sA0, 1, te2, 8192); stg(sA1, 1, te2, 24576); }
        QUAD(1, 1); BARRIER();

        // P4: stage buf0.B0 (te+2); vmcnt gates buf1 'to' readiness
        RD_A(0, 0);
        if (g) { stg(sB0, 0, te2, 32768); stg(sB0, 1, te2, 40960); VMCNT(4); }
        else   { VMCNT(0); }
        QUAD(0, 1); BARRIER();

        // P5: stage buf0.B1(te+2) + buf0.A-ch0(te+2)  [A-ch0 moved from P6]
        RD_A(1, 0); RD_B(1, 0);
        if (g) {
            stg(sB1, 0, te2, 49152); stg(sB1, 1, te2, 57344);
            stg(sA0, 0, te2, 0);     stg(sA1, 0, te2, 16384);
        }
        QUAD(0, 0); BARRIER();

        // P6: no stages (pure compute)
        RD_A(1, 1);
        QUAD(1, 0); BARRIER();

        // P7: stage buf1.A-ch1 (to+2)
        RD_B(1, 1);
        if (g) { stg(sA0, 1, to2, 73728); stg(sA1, 1, to2, 90112); }
        QUAD(1, 1); BARRIER();

        // P8: stage buf1.B0 (to+2); vmcnt gates buf0 te+2 readiness
        RD_A(1, 0);
        if (g) { stg(sB0, 0, to2, 98304); stg(sB0, 1, to2, 106496); VMCNT(4); }
        QUAD(0, 1); BARRIER();
    }

#undef RD_A
#undef RD_B
#undef QUAD

    if constexpr (EPI == 0) {
#pragma unroll
        for (int m = 0; m < 8; ++m) {
            int gr0 = bm * 256 + wr * 128 + m * 16 + lg * 4;
#pragma unroll
            for (int n = 0; n < 4; ++n) {
                int gc = bn * 256 + wc * 64 + n * 16 + lr;
#pragma unroll
                for (int r = 0; r < 4; ++r)
                    C[(size_t)(gr0 + r) * N + gc] = acc[m][n][r];
            }
        }
    } else {
        const int hc = bn * 2 + (wc >> 1);       // 0..47
        const int which = hc >> 4, h = hc & 15;
#pragma unroll
        for (int m = 0; m < 8; ++m) {
            int gr0 = bm * 256 + wr * 128 + m * 16 + lg * 4;   // b*L + l0
            int b = gr0 >> 11, l0 = gr0 & 2047;
            if (which == 2) {                    // V -> [BH][D][L], d unpermuted
#pragma unroll
                for (int n = 0; n < 4; ++n) {
                    int d = (wc & 1) * 64 + n * 16 + lr;
                    us4 pk;
#pragma unroll
                    for (int r = 0; r < 4; ++r) pk[r] = f2bf(acc[m][n][r]);
                    *(us4*)(Vt + ((size_t)(b * 16 + h) * 128 + d) * 2048 + l0) = pk;
                }
            } else {                             // Q/K: rope on lane-local pairs (np, np+1)
                ushort_t* dst = (which == 0) ? Qb : Kb;
                const float sc = (which == 0) ? QK_SCALE : 1.0f;
#pragma unroll
                for (int np = 0; np < 4; np += 2) {
                    int tbl = ((wc & 1) * 2 + (np >> 1)) * 16 + lr;   // orig dim 0..63
                    int p1 = (wc & 1) * 64 + np * 16 + lr;            // permuted d
#pragma unroll
                    for (int r = 0; r < 4; ++r) {
                        float2 cs = rope[(size_t)(l0 + r) * 64 + tbl];
                        float x1 = acc[m][np][r], x2 = acc[m][np + 1][r];
                        size_t base = ((size_t)(b * 16 + h) * 2048 + (l0 + r)) * 128;
                        dst[base + p1]      = f2bf((x1 * cs.x - x2 * cs.y) * sc);
                        dst[base + p1 + 16] = f2bf((x2 * cs.x + x1 * cs.y) * sc);
                    }
                }
            }
        }
    }
}

// ---------------- causal flash attention: 8-wave LDS-shared K/V (R16, verified best) ----------------

__global__ __attribute__((amdgpu_flat_work_group_size(512, 512), amdgpu_waves_per_eu(2, 2)))
void attn_fwd(const ushort_t* __restrict__ Qb, const ushort_t* __restrict__ Kb,
              const ushort_t* __restrict__ Vt, ushort_t* __restrict__ AO) {
    constexpr int L = 2048;
    __shared__ __attribute__((aligned(16))) char smem[131072];  // [buf][K 32KB | V 32KB]

    const int tid  = threadIdx.x;
    const int lane = tid & 63, wid = tid >> 6;
    const int q_l  = lane & 31;
    const int hi   = lane >> 5;

    const int bid  = blockIdx.x;
    const int hl   = (bid >> 3) & 7;
    const int pr   = bid >> 6;
    const int head = (bid & 7) * 8 + hl;

    const ushort_t* Qh = Qb + (size_t)head * L * 128;
    const char*     KhB = (const char*)(Kb + (size_t)head * L * 128);
    const char*     VhB = (const char*)(Vt + (size_t)head * 128 * L);
    const int b = head >> 4, h = head & 15;

    int rKV[4], cK[4], cV[4];
#pragma unroll
    for (int i = 0; i < 4; ++i) {
        rKV[i] = wid * 16 + i * 4 + (lane >> 4);                  // rows 0..127
        cK[i]  = ((lane & 15) << 4) ^ ((rKV[i] & 7) << 4);        // pre-swizzled src col
        cV[i]  = cK[i];
    }
    const int kdst = wid * 4096;
    const int vdst = 32768 + wid * 4096;

    for (int ph = 0; ph < 2; ++ph) {
        const int s    = ph ? (7 - pr) : pr;
        const int q0w  = s * 256 + wid * 32;
        const int nch  = 2 * s + 2;            // 128-row chunks

        bf16x8 qf[8];
#pragma unroll
        for (int sb = 0; sb < 8; ++sb)
            qf[sb] = *(const bf16x8*)(Qh + (size_t)(q0w + q_l) * 128 + sb * 16 + hi * 8);

        f32x16 o[4];
#pragma unroll
        for (int d0 = 0; d0 < 4; ++d0) o[d0] = (f32x16)(0.f);
        float m_ = -__builtin_inff(), l_ = 0.f;

        __syncthreads();                        // phase boundary (buffers quiescent)
#pragma unroll
        for (int i = 0; i < 4; ++i) {
            gload16(KhB + (size_t)rKV[i] * 256 + cK[i], smem + kdst + i * 1024);
            gload16(VhB + (size_t)rKV[i] * 4096 + cV[i], smem + vdst + i * 1024);
        }

        for (int c = 0; c < nch; ++c) {
            __syncthreads();                    // stage(c) landed
            const int kb = (c & 1) * 65536;
            const int nb = ((c + 1) & 1) * 65536;
            if (c + 1 < nch) {
                const int kn = 128 * (c + 1);
#pragma unroll
                for (int i = 0; i < 4; ++i) {
                    gload16(KhB + (size_t)(kn + rKV[i]) * 256 + cK[i], smem + nb + kdst + i * 1024);
                    gload16(VhB + (size_t)rKV[i] * 4096 + (size_t)kn * 2 + cV[i], smem + nb + vdst + i * 1024);
                }
            }

#pragma unroll
            for (int sub = 0; sub < 2; ++sub) {
                const int k0 = 128 * c + 64 * sub;
                if (k0 > q0w + 31) continue;
                const bool do1 = (k0 + 32 <= q0w + 31);
                const int kloc = sub * 64;

                f32x16 s0, s1;
                {
                    bf16x8 kf[8];
#pragma unroll
                    for (int sb = 0; sb < 8; ++sb) {
                        int off = kb + (kloc + q_l) * 256 + ((sb * 32 + hi * 16) ^ ((q_l & 7) << 4));
                        kf[sb] = *(const bf16x8*)(smem + off);
                    }
                    f32x16 sA = (f32x16)(0.f), sB = (f32x16)(0.f);
#pragma unroll
                    for (int sb = 0; sb < 8; sb += 2) {
                        sA = __builtin_amdgcn_mfma_f32_32x32x16_bf16(kf[sb],     qf[sb],     sA, 0, 0, 0);
                        sB = __builtin_amdgcn_mfma_f32_32x32x16_bf16(kf[sb + 1], qf[sb + 1], sB, 0, 0, 0);
                    }
                    s0 = sA + sB;
                }
                if (do1) {
                    bf16x8 kf[8];
#pragma unroll
                    for (int sb = 0; sb < 8; ++sb) {
                        int off = kb + (kloc + 32 + q_l) * 256 + ((sb * 32 + hi * 16) ^ ((q_l & 7) << 4));
                        kf[sb] = *(const bf16x8*)(smem + off);
                    }
                    f32x16 sA = (f32x16)(0.f), sB = (f32x16)(0.f);
#pragma unroll
                    for (int sb = 0; sb < 8; sb += 2) {
                        sA = __builtin_amdgcn_mfma_f32_32x32x16_bf16(kf[sb],     qf[sb],     sA, 0, 0, 0);
                        sB = __builtin_amdgcn_mfma_f32_32x32x16_bf16(kf[sb + 1], qf[sb + 1], sB, 0, 0, 0);
                    }
                    s1 = sA + sB;
                }

                if (k0 + 31 > q0w) {
#pragma unroll
                    for (int r = 0; r < 16; ++r) {
                        int crow = (r & 3) + 8 * (r >> 2) + 4 * hi;
                        if (k0 + crow > q0w + q_l) s0[r] = NEG_BIG;
                    }
                }
                if (do1 && (k0 + 63 > q0w)) {
#pragma unroll
                    for (int r = 0; r < 16; ++r) {
                        int crow = (r & 3) + 8 * (r >> 2) + 4 * hi;
                        if (k0 + 32 + crow > q0w + q_l) s1[r] = NEG_BIG;
                    }
                }

                float t8[8];
#pragma unroll
                for (int r = 0; r < 8; ++r) t8[r] = fmaxf(s0[r], s0[r + 8]);
                if (do1)
#pragma unroll
                    for (int r = 0; r < 8; ++r) t8[r] = fmaxf(t8[r], fmaxf(s1[r], s1[r + 8]));
#pragma unroll
                for (int r = 0; r < 4; ++r) t8[r] = fmaxf(t8[r], t8[r + 4]);
                float tmax = fmaxf(fmaxf(t8[0], t8[1]), fmaxf(t8[2], t8[3]));
                tmax = fmaxf(tmax, __shfl_xor(tmax, 32, 64));

                if (!__all(tmax <= m_ + 8.f)) {
                    float mn = fmaxf(m_, tmax);
                    float alpha = exp2f(m_ - mn);
                    m_ = mn;
                    l_ *= alpha;
#pragma unroll
                    for (int d0 = 0; d0 < 4; ++d0)
#pragma unroll
                        for (int r = 0; r < 16; ++r) o[d0][r] *= alpha;
                }

                float rs = 0.f;
#pragma unroll
                for (int r = 0; r < 16; ++r) { s0[r] = exp2f(s0[r] - m_); rs += s0[r]; }
                if (do1)
#pragma unroll
                    for (int r = 0; r < 16; ++r) { s1[r] = exp2f(s1[r] - m_); rs += s1[r]; }
                rs += __shfl_xor(rs, 32, 64);
                l_ += rs;

                // ---- pack P -> bf16 B-frags via cvt_pk + permlane32_swap (T12) ----
                bf16x8 pfA[2], pfB[2];
                {
                    unsigned int pk[8];
#pragma unroll
                    for (int i = 0; i < 8; ++i) pk[i] = pk2bf(s0[2 * i], s0[2 * i + 1]);
#pragma unroll
                    for (int ks = 0; ks < 2; ++ks) {
                        unsigned int a0 = pk[ks * 4 + 0], b0 = pk[ks * 4 + 2];
                        unsigned int a1 = pk[ks * 4 + 1], b1 = pk[ks * 4 + 3];
                        asm("v_permlane32_swap_b32 %0, %1" : "+v"(a0), "+v"(b0));
                        asm("v_permlane32_swap_b32 %0, %1" : "+v"(a1), "+v"(b1));
                        ui4 dw; dw[0] = a0; dw[1] = a1; dw[2] = b0; dw[3] = b1;
                        pfA[ks] = __builtin_bit_cast(bf16x8, dw);
                    }
                }
                if (do1) {
                    unsigned int pk[8];
#pragma unroll
                    for (int i = 0; i < 8; ++i) pk[i] = pk2bf(s1[2 * i], s1[2 * i + 1]);
#pragma unroll
                    for (int ks = 0; ks < 2; ++ks) {
                        unsigned int a0 = pk[ks * 4 + 0], b0 = pk[ks * 4 + 2];
                        unsigned int a1 = pk[ks * 4 + 1], b1 = pk[ks * 4 + 3];
                        asm("v_permlane32_swap_b32 %0, %1" : "+v"(a0), "+v"(b0));
                        asm("v_permlane32_swap_b32 %0, %1" : "+v"(a1), "+v"(b1));
                        ui4 dw; dw[0] = a0; dw[1] = a1; dw[2] = b0; dw[3] = b1;
                        pfB[ks] = __builtin_bit_cast(bf16x8, dw);
                    }
                }

                const int vb = kb + 32768;
#pragma unroll
                for (int d0 = 0; d0 < 4; ++d0) {
                    int d = d0 * 32 + q_l;
#pragma unroll
                    for (int ks = 0; ks < 2; ++ks) {
                        int off = vb + d * 256 + ((sub * 128 + ks * 32 + hi * 16) ^ ((d & 7) << 4));
                        bf16x8 vf = *(const bf16x8*)(smem + off);
                        o[d0] = __builtin_amdgcn_mfma_f32_32x32x16_bf16(vf, pfA[ks], o[d0], 0, 0, 0);
                    }
                    if (do1) {
#pragma unroll
                        for (int ks = 0; ks < 2; ++ks) {
                            int off = vb + d * 256 + ((sub * 128 + (2 + ks) * 32 + hi * 16) ^ ((d & 7) << 4));
                            bf16x8 vf = *(const bf16x8*)(smem + off);
                            o[d0] = __builtin_amdgcn_mfma_f32_32x32x16_bf16(vf, pfB[ks], o[d0], 0, 0, 0);
                        }
                    }
                }
            }
        }

        // ---- epilogue ----
        const float inv = 1.f / l_;
        const size_t rowbase = ((size_t)(b * 2048 + q0w + q_l)) * 2048 + h * 128;
#pragma unroll
        for (int d0 = 0; d0 < 4; ++d0)
#pragma unroll
            for (int g = 0; g < 4; ++g) {
                us4 v;
#pragma unroll
                for (int r = 0; r < 4; ++r) v[r] = f2bf(o[d0][g * 4 + r] * inv);
                *(us4*)(AO + rowbase + d0 * 32 + g * 8 + hi * 4) = v;
            }
    }
}

// ---------------- launcher ----------------

extern "C" void kernel_launch(void* const* d_in, const int* in_sizes, int n_in,
                              void* d_out, int out_size, void* d_ws, size_t ws_size,
                              hipStream_t stream) {
    const float* x    = (const float*)d_in[0];   // [4,2048,2048]
    const float* Wqkv = (const float*)d_in[1];   // [2048,6144]
    const float* Wo   = (const float*)d_in[2];   // [2048,2048]
    float* out = (float*)d_out;                  // [4,2048,2048] fp32

    char* w = (char*)d_ws;
    ushort_t* xb   = (ushort_t*)(w);               // x bf16             33,554,432 B
    ushort_t* W1t  = (ushort_t*)(w + 33554432);    // Wqkv^T bf16 (QK-permuted) 25,165,824 B
    ushort_t* Wot  = (ushort_t*)(w + 58720256);    // Wo^T bf16           8,388,608 B
    ushort_t* Qb   = (ushort_t*)(w + 67108864);    // Q roped [BH][L][D'] 33,554,432 B
    ushort_t* Kbf  = (ushort_t*)(w + 100663296);   // K roped [BH][L][D'] 33,554,432 B
    ushort_t* Vt   = (ushort_t*)(w + 134217728);   // V^T    [BH][D][L]  33,554,432 B
    ushort_t* AO   = (ushort_t*)(w + 167772160);   // attn out bf16      33,554,432 B
    float2*   rope = (float2*)(w + 201326592);     // [L][64] cos/sin     1,048,576 B

    cvt_bf16_kernel<<<16384, 256, 0, stream>>>((const float4*)x, (us4*)xb, 4194304);
    transpose_wqkv<<<dim3(96, 32), 256, 0, stream>>>(Wqkv, W1t);
    transpose_bf16<<<dim3(32, 32), 256, 0, stream>>>(Wo, Wot, 2048, 2048);
    rope_table_kernel<<<512, 256, 0, stream>>>(rope);

    // qkv GEMM (256^2 8-phase, widened staging windows) + fused rope/reshape epilogue
    gemm256<1><<<768, 512, 0, stream>>>(xb, W1t, 8192, 6144, 2048,
                                        nullptr, Qb, Kbf, Vt, rope);
    // causal flash attention: 8-wave blocks, LDS-shared K/V, permlane pack
    attn_fwd<<<256, 512, 0, stream>>>(Qb, Kbf, Vt, AO);
    // output projection (256^2 8-phase, widened staging windows)
    gemm256<0><<<256, 512, 0, stream>>>(AO, Wot, 8192, 2048, 2048,
                                        out, nullptr, nullptr, nullptr, nullptr);
}

// Round 20
// 409.618 us; speedup vs baseline: 1.0102x; 1.0102x over previous
//
#include <hip/hip_runtime.h>
#include <hip/hip_bf16.h>
#include <stdint.h>

typedef unsigned short ushort_t;
typedef __bf16 bf16x8 __attribute__((ext_vector_type(8)));
typedef float    f32x4 __attribute__((ext_vector_type(4)));
typedef float   f32x16 __attribute__((ext_vector_type(16)));
typedef unsigned short us4 __attribute__((ext_vector_type(4)));
typedef unsigned int ui4 __attribute__((ext_vector_type(4)));

#define QK_SCALE 0.12751744f   /* log2(e) / sqrt(128) : folded into Q so softmax uses exp2 */
#define NEG_BIG  -1e30f

#define BARRIER() do { asm volatile("" ::: "memory"); __builtin_amdgcn_s_barrier(); asm volatile("" ::: "memory"); } while (0)
#define VMCNT(N)  asm volatile("s_waitcnt vmcnt(" #N ")" ::: "memory")
#define MFMA16(d, a, b) d = __builtin_amdgcn_mfma_f32_16x16x32_bf16(a, b, d, 0, 0, 0)

__device__ __forceinline__ unsigned short f2bf(float f) {
    union { float f; unsigned int u; } v; v.f = f;
    unsigned int u = v.u;
    return (unsigned short)((u + 0x7FFFu + ((u >> 16) & 1u)) >> 16);  // RNE
}

// HW packed convert: dst.lo = bf16(a), dst.hi = bf16(b)
__device__ __forceinline__ unsigned int pk2bf(float a, float b) {
    unsigned int r;
    asm("v_cvt_pk_bf16_f32 %0, %1, %2" : "=v"(r) : "v"(a), "v"(b));
    return r;
}

// async global->LDS, 16B per lane. LDS dest is wave-uniform base + lane*16.
__device__ __forceinline__ void gload16(const void* g, void* l) {
    __builtin_amdgcn_global_load_lds(
        (__attribute__((address_space(1))) void*)(uintptr_t)g,
        (__attribute__((address_space(3))) void*)(uint32_t)(uintptr_t)l,
        16, 0, 0);
}

// ---------------- prep kernels ----------------

__global__ __launch_bounds__(256) void cvt_bf16_kernel(
    const float4* __restrict__ in, us4* __restrict__ out, int n4) {
    int i = blockIdx.x * 256 + threadIdx.x;
    if (i >= n4) return;
    float4 v = in[i];
    us4 o; o[0] = f2bf(v.x); o[1] = f2bf(v.y); o[2] = f2bf(v.z); o[3] = f2bf(v.w);
    out[i] = o;
}

// generic: in [R][C] fp32 -> out [C][R] bf16
__global__ __launch_bounds__(256) void transpose_bf16(
    const float* __restrict__ in, ushort_t* __restrict__ out, int R, int C) {
    __shared__ float t[64][65];
    int c0 = blockIdx.x * 64, r0 = blockIdx.y * 64;
    int cc = threadIdx.x & 63, rr = threadIdx.x >> 6;
#pragma unroll
    for (int i = 0; i < 16; ++i) {
        int r = i * 4 + rr;
        t[r][cc] = in[(size_t)(r0 + r) * C + c0 + cc];
    }
    __syncthreads();
#pragma unroll
    for (int i = 0; i < 16; ++i) {
        int r = i * 4 + rr;
        out[(size_t)(c0 + r) * R + r0 + cc] = f2bf(t[cc][r]);
    }
}

// Wqkv transpose with Q/K head-dim bit-permutation (R8-verified, QK^T-invariant)
__global__ __launch_bounds__(256) void transpose_wqkv(
    const float* __restrict__ in /*[2048][6144]*/, ushort_t* __restrict__ out /*[6144][2048]*/) {
    __shared__ float t[64][65];
    int c0 = blockIdx.x * 64, r0 = blockIdx.y * 64;
    int cc = threadIdx.x & 63, rr = threadIdx.x >> 6;
    int n = c0 + cc;
    int which = n >> 11;
    int src = n;
    if (which < 2) {
        int h = (n >> 7) & 15, p = n & 127;
        int po = (p & 15) | (((p >> 5) & 3) << 4) | (((p >> 4) & 1) << 6);
        src = (which << 11) + (h << 7) + po;
    }
#pragma unroll
    for (int i = 0; i < 16; ++i) {
        int r = i * 4 + rr;
        t[r][cc] = in[(size_t)(r0 + r) * 6144 + src];
    }
    __syncthreads();
#pragma unroll
    for (int i = 0; i < 16; ++i) {
        int r = i * 4 + rr;
        out[(size_t)(c0 + r) * 2048 + r0 + cc] = f2bf(t[cc][r]);
    }
}

// rope table: [L][64] of (cos, sin)
__global__ __launch_bounds__(256) void rope_table_kernel(float2* __restrict__ rope) {
    int i = blockIdx.x * 256 + threadIdx.x;     // L*64 = 131072 exactly
    int l = i >> 6, j = i & 63;
    float inv = exp2f((float)j * -0.20762050593046f);  // 10000^(-j/64)
    float f = (float)l * inv;
    rope[i] = make_float2(cosf(f), sinf(f));
}

// ---------------- 256x256 8-phase GEMM: single barrier per phase (R16, verified best) ----------------

template <int EPI>
__global__ __launch_bounds__(512, 2)
void gemm256(const ushort_t* __restrict__ A, const ushort_t* __restrict__ Bt,
             int M, int N, int K,
             float* __restrict__ C,
             ushort_t* __restrict__ Qb, ushort_t* __restrict__ Kb,
             ushort_t* __restrict__ Vt, const float2* __restrict__ rope) {
    __shared__ __attribute__((aligned(16))) char lds[131072];

    const int tid  = threadIdx.x;
    const int lane = tid & 63, wid = tid >> 6;
    const int lr = lane & 15, lg = lane >> 4;
    const int wr = wid >> 2, wc = wid & 3;        // wave grid 2(M) x 4(N)

    const int nbn = N >> 8;
    const int nwg = gridDim.x;
    const int bid = blockIdx.x;
    const int wg  = (bid & 7) * (nwg >> 3) + (bid >> 3);   // XCD-contiguous
    const int bm  = wg / nbn, bn = wg % nbn;

    const int srow = tid >> 3;                                   // 0..63
    const int scol = ((tid & 7) << 4) ^ ((srow & 7) << 4);
    const size_t rowK2 = (size_t)K * 2;
    const char* sA0 = (const char*)A + ((size_t)(bm * 256 + srow)) * rowK2 + scol;
    const char* sA1 = sA0 + 128 * rowK2;
    const char* sB0 = (const char*)Bt + ((size_t)(bn * 256 + srow)) * rowK2 + scol;
    const char* sB1 = sB0 + 128 * rowK2;

    auto stg = [&](const char* s, int ch, int kt, int dst) {
        gload16(s + (size_t)(ch * 64) * rowK2 + (size_t)kt * 128, lds + dst + wid * 1024);
    };

    const int xk0 = (lg * 16) ^ ((lr & 7) << 4);
    const int xk1 = (64 + lg * 16) ^ ((lr & 7) << 4);
    const int rowA = wr * 16384 + lr * 128;
    const int rowB = 32768 + (wc >> 1) * 16384 + ((wc & 1) * 64 + lr) * 128;

    auto rdA = [&](int bu, int mi, int kk) -> bf16x8 {
        return *(const bf16x8*)(lds + bu * 65536 + rowA + mi * 2048 + (kk ? xk1 : xk0));
    };
    auto rdB = [&](int bu, int ni, int kk) -> bf16x8 {
        return *(const bf16x8*)(lds + bu * 65536 + rowB + ni * 2048 + (kk ? xk1 : xk0));
    };

    f32x4 acc[8][4];
#pragma unroll
    for (int m = 0; m < 8; ++m)
#pragma unroll
        for (int n = 0; n < 4; ++n) acc[m][n] = (f32x4){0.f, 0.f, 0.f, 0.f};

    bf16x8 aF[4][2], bF[2][2];

#define RD_A(BU, MH) do { _Pragma("unroll") for (int mi = 0; mi < 4; ++mi) { \
        aF[mi][0] = rdA(BU, (MH)*4 + mi, 0); aF[mi][1] = rdA(BU, (MH)*4 + mi, 1); } } while (0)
#define RD_B(BU, NH) do { _Pragma("unroll") for (int ni = 0; ni < 2; ++ni) { \
        bF[ni][0] = rdB(BU, (NH)*2 + ni, 0); bF[ni][1] = rdB(BU, (NH)*2 + ni, 1); } } while (0)
#define QUAD(MH, NH) do { __builtin_amdgcn_s_setprio(1); \
        _Pragma("unroll") for (int kk = 0; kk < 2; ++kk) \
        _Pragma("unroll") for (int mi = 0; mi < 4; ++mi) \
        _Pragma("unroll") for (int ni = 0; ni < 2; ++ni) \
            MFMA16(acc[(MH)*4 + mi][(NH)*2 + ni], aF[mi][kk], bF[ni][kk]); \
        __builtin_amdgcn_s_setprio(0); } while (0)

    // ---- prologue: buf0 <- tile0 (8 chunks); buf1 <- tile1 {A0c1,A1c1,B0c0,B0c1} ----
    stg(sA0, 0, 0, 0);     stg(sA0, 1, 0, 8192);
    stg(sA1, 0, 0, 16384); stg(sA1, 1, 0, 24576);
    stg(sB0, 0, 0, 32768); stg(sB0, 1, 0, 40960);
    stg(sB1, 0, 0, 49152); stg(sB1, 1, 0, 57344);
    stg(sA0, 1, 1, 73728); stg(sA1, 1, 1, 90112);
    stg(sB0, 0, 1, 98304); stg(sB0, 1, 1, 106496);
    VMCNT(4);
    BARRIER();

    const int NIT = K / 128;
    for (int i = 0; i < NIT; ++i) {
        const int to = 2 * i + 1, te2 = 2 * i + 2, to2 = 2 * i + 3;
        const bool g = (i + 1 < NIT);

        // P1
        RD_A(0, 0); RD_B(0, 0);
        stg(sB1, 0, to, 114688); stg(sB1, 1, to, 122880);
        QUAD(0, 0); BARRIER();

        // P2
        RD_A(0, 1);
        stg(sA0, 0, to, 65536); stg(sA1, 0, to, 81920);
        QUAD(1, 0); BARRIER();

        // P3
        RD_B(0, 1);
        if (g) { stg(sA0, 1, te2, 8192); stg(sA1, 1, te2, 24576); }
        QUAD(1, 1); BARRIER();

        // P4 — vmcnt gates buf1 'to' readiness (all waves vmcnt before the shared barrier)
        RD_A(0, 0);
        if (g) { stg(sB0, 0, te2, 32768); stg(sB0, 1, te2, 40960); VMCNT(4); }
        else   { VMCNT(0); }
        QUAD(0, 1); BARRIER();

        // P5
        RD_A(1, 0); RD_B(1, 0);
        if (g) { stg(sB1, 0, te2, 49152); stg(sB1, 1, te2, 57344); }
        QUAD(0, 0); BARRIER();

        // P6
        RD_A(1, 1);
        if (g) { stg(sA0, 0, te2, 0); stg(sA1, 0, te2, 16384); }
        QUAD(1, 0); BARRIER();

        // P7
        RD_B(1, 1);
        if (g) { stg(sA0, 1, to2, 73728); stg(sA1, 1, to2, 90112); }
        QUAD(1, 1); BARRIER();

        // P8 — vmcnt gates buf0 te+2 readiness
        RD_A(1, 0);
        if (g) { stg(sB0, 0, to2, 98304); stg(sB0, 1, to2, 106496); VMCNT(4); }
        QUAD(0, 1); BARRIER();
    }

#undef RD_A
#undef RD_B
#undef QUAD

    if constexpr (EPI == 0) {
#pragma unroll
        for (int m = 0; m < 8; ++m) {
            int gr0 = bm * 256 + wr * 128 + m * 16 + lg * 4;
#pragma unroll
            for (int n = 0; n < 4; ++n) {
                int gc = bn * 256 + wc * 64 + n * 16 + lr;
#pragma unroll
                for (int r = 0; r < 4; ++r)
                    C[(size_t)(gr0 + r) * N + gc] = acc[m][n][r];
            }
        }
    } else {
        const int hc = bn * 2 + (wc >> 1);       // 0..47
        const int which = hc >> 4, h = hc & 15;
#pragma unroll
        for (int m = 0; m < 8; ++m) {
            int gr0 = bm * 256 + wr * 128 + m * 16 + lg * 4;   // b*L + l0
            int b = gr0 >> 11, l0 = gr0 & 2047;
            if (which == 2) {                    // V -> [BH][D][L], d unpermuted
#pragma unroll
                for (int n = 0; n < 4; ++n) {
                    int d = (wc & 1) * 64 + n * 16 + lr;
                    us4 pk;
#pragma unroll
                    for (int r = 0; r < 4; ++r) pk[r] = f2bf(acc[m][n][r]);
                    *(us4*)(Vt + ((size_t)(b * 16 + h) * 128 + d) * 2048 + l0) = pk;
                }
            } else {                             // Q/K: rope on lane-local pairs (np, np+1)
                ushort_t* dst = (which == 0) ? Qb : Kb;
                const float sc = (which == 0) ? QK_SCALE : 1.0f;
#pragma unroll
                for (int np = 0; np < 4; np += 2) {
                    int tbl = ((wc & 1) * 2 + (np >> 1)) * 16 + lr;   // orig dim 0..63
                    int p1 = (wc & 1) * 64 + np * 16 + lr;            // permuted d
#pragma unroll
                    for (int r = 0; r < 4; ++r) {
                        float2 cs = rope[(size_t)(l0 + r) * 64 + tbl];
                        float x1 = acc[m][np][r], x2 = acc[m][np + 1][r];
                        size_t base = ((size_t)(b * 16 + h) * 2048 + (l0 + r)) * 128;
                        dst[base + p1]      = f2bf((x1 * cs.x - x2 * cs.y) * sc);
                        dst[base + p1 + 16] = f2bf((x2 * cs.x + x1 * cs.y) * sc);
                    }
                }
            }
        }
    }
}

// ---------------- causal flash attention: 8-wave LDS-shared K/V (R16, verified best) ----------------

__global__ __attribute__((amdgpu_flat_work_group_size(512, 512), amdgpu_waves_per_eu(2, 2)))
void attn_fwd(const ushort_t* __restrict__ Qb, const ushort_t* __restrict__ Kb,
              const ushort_t* __restrict__ Vt, ushort_t* __restrict__ AO) {
    constexpr int L = 2048;
    __shared__ __attribute__((aligned(16))) char smem[131072];  // [buf][K 32KB | V 32KB]

    const int tid  = threadIdx.x;
    const int lane = tid & 63, wid = tid >> 6;
    const int q_l  = lane & 31;
    const int hi   = lane >> 5;

    const int bid  = blockIdx.x;
    const int hl   = (bid >> 3) & 7;
    const int pr   = bid >> 6;
    const int head = (bid & 7) * 8 + hl;

    const ushort_t* Qh = Qb + (size_t)head * L * 128;
    const char*     KhB = (const char*)(Kb + (size_t)head * L * 128);
    const char*     VhB = (const char*)(Vt + (size_t)head * 128 * L);
    const int b = head >> 4, h = head & 15;

    int rKV[4], cK[4], cV[4];
#pragma unroll
    for (int i = 0; i < 4; ++i) {
        rKV[i] = wid * 16 + i * 4 + (lane >> 4);                  // rows 0..127
        cK[i]  = ((lane & 15) << 4) ^ ((rKV[i] & 7) << 4);        // pre-swizzled src col
        cV[i]  = cK[i];
    }
    const int kdst = wid * 4096;
    const int vdst = 32768 + wid * 4096;

    for (int ph = 0; ph < 2; ++ph) {
        const int s    = ph ? (7 - pr) : pr;
        const int q0w  = s * 256 + wid * 32;
        const int nch  = 2 * s + 2;            // 128-row chunks

        bf16x8 qf[8];
#pragma unroll
        for (int sb = 0; sb < 8; ++sb)
            qf[sb] = *(const bf16x8*)(Qh + (size_t)(q0w + q_l) * 128 + sb * 16 + hi * 8);

        f32x16 o[4];
#pragma unroll
        for (int d0 = 0; d0 < 4; ++d0) o[d0] = (f32x16)(0.f);
        float m_ = -__builtin_inff(), l_ = 0.f;

        __syncthreads();                        // phase boundary (buffers quiescent)
#pragma unroll
        for (int i = 0; i < 4; ++i) {
            gload16(KhB + (size_t)rKV[i] * 256 + cK[i], smem + kdst + i * 1024);
            gload16(VhB + (size_t)rKV[i] * 4096 + cV[i], smem + vdst + i * 1024);
        }

        for (int c = 0; c < nch; ++c) {
            __syncthreads();                    // stage(c) landed
            const int kb = (c & 1) * 65536;
            const int nb = ((c + 1) & 1) * 65536;
            if (c + 1 < nch) {
                const int kn = 128 * (c + 1);
#pragma unroll
                for (int i = 0; i < 4; ++i) {
                    gload16(KhB + (size_t)(kn + rKV[i]) * 256 + cK[i], smem + nb + kdst + i * 1024);
                    gload16(VhB + (size_t)rKV[i] * 4096 + (size_t)kn * 2 + cV[i], smem + nb + vdst + i * 1024);
                }
            }

#pragma unroll
            for (int sub = 0; sub < 2; ++sub) {
                const int k0 = 128 * c + 64 * sub;
                if (k0 > q0w + 31) continue;
                const bool do1 = (k0 + 32 <= q0w + 31);
                const int kloc = sub * 64;

                f32x16 s0, s1;
                {
                    bf16x8 kf[8];
#pragma unroll
                    for (int sb = 0; sb < 8; ++sb) {
                        int off = kb + (kloc + q_l) * 256 + ((sb * 32 + hi * 16) ^ ((q_l & 7) << 4));
                        kf[sb] = *(const bf16x8*)(smem + off);
                    }
                    f32x16 sA = (f32x16)(0.f), sB = (f32x16)(0.f);
#pragma unroll
                    for (int sb = 0; sb < 8; sb += 2) {
                        sA = __builtin_amdgcn_mfma_f32_32x32x16_bf16(kf[sb],     qf[sb],     sA, 0, 0, 0);
                        sB = __builtin_amdgcn_mfma_f32_32x32x16_bf16(kf[sb + 1], qf[sb + 1], sB, 0, 0, 0);
                    }
                    s0 = sA + sB;
                }
                if (do1) {
                    bf16x8 kf[8];
#pragma unroll
                    for (int sb = 0; sb < 8; ++sb) {
                        int off = kb + (kloc + 32 + q_l) * 256 + ((sb * 32 + hi * 16) ^ ((q_l & 7) << 4));
                        kf[sb] = *(const bf16x8*)(smem + off);
                    }
                    f32x16 sA = (f32x16)(0.f), sB = (f32x16)(0.f);
#pragma unroll
                    for (int sb = 0; sb < 8; sb += 2) {
                        sA = __builtin_amdgcn_mfma_f32_32x32x16_bf16(kf[sb],     qf[sb],     sA, 0, 0, 0);
                        sB = __builtin_amdgcn_mfma_f32_32x32x16_bf16(kf[sb + 1], qf[sb + 1], sB, 0, 0, 0);
                    }
                    s1 = sA + sB;
                }

                if (k0 + 31 > q0w) {
#pragma unroll
                    for (int r = 0; r < 16; ++r) {
                        int crow = (r & 3) + 8 * (r >> 2) + 4 * hi;
                        if (k0 + crow > q0w + q_l) s0[r] = NEG_BIG;
                    }
                }
                if (do1 && (k0 + 63 > q0w)) {
#pragma unroll
                    for (int r = 0; r < 16; ++r) {
                        int crow = (r & 3) + 8 * (r >> 2) + 4 * hi;
                        if (k0 + 32 + crow > q0w + q_l) s1[r] = NEG_BIG;
                    }
                }

                float t8[8];
#pragma unroll
                for (int r = 0; r < 8; ++r) t8[r] = fmaxf(s0[r], s0[r + 8]);
                if (do1)
#pragma unroll
                    for (int r = 0; r < 8; ++r) t8[r] = fmaxf(t8[r], fmaxf(s1[r], s1[r + 8]));
#pragma unroll
                for (int r = 0; r < 4; ++r) t8[r] = fmaxf(t8[r], t8[r + 4]);
                float tmax = fmaxf(fmaxf(t8[0], t8[1]), fmaxf(t8[2], t8[3]));
                tmax = fmaxf(tmax, __shfl_xor(tmax, 32, 64));

                if (!__all(tmax <= m_ + 8.f)) {
                    float mn = fmaxf(m_, tmax);
                    float alpha = exp2f(m_ - mn);
                    m_ = mn;
                    l_ *= alpha;
#pragma unroll
                    for (int d0 = 0; d0 < 4; ++d0)
#pragma unroll
                        for (int r = 0; r < 16; ++r) o[d0][r] *= alpha;
                }

                float rs = 0.f;
#pragma unroll
                for (int r = 0; r < 16; ++r) { s0[r] = exp2f(s0[r] - m_); rs += s0[r]; }
                if (do1)
#pragma unroll
                    for (int r = 0; r < 16; ++r) { s1[r] = exp2f(s1[r] - m_); rs += s1[r]; }
                rs += __shfl_xor(rs, 32, 64);
                l_ += rs;

                // ---- pack P -> bf16 B-frags via cvt_pk + permlane32_swap (T12) ----
                bf16x8 pfA[2], pfB[2];
                {
                    unsigned int pk[8];
#pragma unroll
                    for (int i = 0; i < 8; ++i) pk[i] = pk2bf(s0[2 * i], s0[2 * i + 1]);
#pragma unroll
                    for (int ks = 0; ks < 2; ++ks) {
                        unsigned int a0 = pk[ks * 4 + 0], b0 = pk[ks * 4 + 2];
                        unsigned int a1 = pk[ks * 4 + 1], b1 = pk[ks * 4 + 3];
                        asm("v_permlane32_swap_b32 %0, %1" : "+v"(a0), "+v"(b0));
                        asm("v_permlane32_swap_b32 %0, %1" : "+v"(a1), "+v"(b1));
                        ui4 dw; dw[0] = a0; dw[1] = a1; dw[2] = b0; dw[3] = b1;
                        pfA[ks] = __builtin_bit_cast(bf16x8, dw);
                    }
                }
                if (do1) {
                    unsigned int pk[8];
#pragma unroll
                    for (int i = 0; i < 8; ++i) pk[i] = pk2bf(s1[2 * i], s1[2 * i + 1]);
#pragma unroll
                    for (int ks = 0; ks < 2; ++ks) {
                        unsigned int a0 = pk[ks * 4 + 0], b0 = pk[ks * 4 + 2];
                        unsigned int a1 = pk[ks * 4 + 1], b1 = pk[ks * 4 + 3];
                        asm("v_permlane32_swap_b32 %0, %1" : "+v"(a0), "+v"(b0));
                        asm("v_permlane32_swap_b32 %0, %1" : "+v"(a1), "+v"(b1));
                        ui4 dw; dw[0] = a0; dw[1] = a1; dw[2] = b0; dw[3] = b1;
                        pfB[ks] = __builtin_bit_cast(bf16x8, dw);
                    }
                }

                const int vb = kb + 32768;
#pragma unroll
                for (int d0 = 0; d0 < 4; ++d0) {
                    int d = d0 * 32 + q_l;
#pragma unroll
                    for (int ks = 0; ks < 2; ++ks) {
                        int off = vb + d * 256 + ((sub * 128 + ks * 32 + hi * 16) ^ ((d & 7) << 4));
                        bf16x8 vf = *(const bf16x8*)(smem + off);
                        o[d0] = __builtin_amdgcn_mfma_f32_32x32x16_bf16(vf, pfA[ks], o[d0], 0, 0, 0);
                    }
                    if (do1) {
#pragma unroll
                        for (int ks = 0; ks < 2; ++ks) {
                            int off = vb + d * 256 + ((sub * 128 + (2 + ks) * 32 + hi * 16) ^ ((d & 7) << 4));
                            bf16x8 vf = *(const bf16x8*)(smem + off);
                            o[d0] = __builtin_amdgcn_mfma_f32_32x32x16_bf16(vf, pfB[ks], o[d0], 0, 0, 0);
                        }
                    }
                }
            }
        }

        // ---- epilogue ----
        const float inv = 1.f / l_;
        const size_t rowbase = ((size_t)(b * 2048 + q0w + q_l)) * 2048 + h * 128;
#pragma unroll
        for (int d0 = 0; d0 < 4; ++d0)
#pragma unroll
            for (int g = 0; g < 4; ++g) {
                us4 v;
#pragma unroll
                for (int r = 0; r < 4; ++r) v[r] = f2bf(o[d0][g * 4 + r] * inv);
                *(us4*)(AO + rowbase + d0 * 32 + g * 8 + hi * 4) = v;
            }
    }
}

// ---------------- launcher ----------------

extern "C" void kernel_launch(void* const* d_in, const int* in_sizes, int n_in,
                              void* d_out, int out_size, void* d_ws, size_t ws_size,
                              hipStream_t stream) {
    const float* x    = (const float*)d_in[0];   // [4,2048,2048]
    const float* Wqkv = (const float*)d_in[1];   // [2048,6144]
    const float* Wo   = (const float*)d_in[2];   // [2048,2048]
    float* out = (float*)d_out;                  // [4,2048,2048] fp32

    char* w = (char*)d_ws;
    ushort_t* xb   = (ushort_t*)(w);               // x bf16             33,554,432 B
    ushort_t* W1t  = (ushort_t*)(w + 33554432);    // Wqkv^T bf16 (QK-permuted) 25,165,824 B
    ushort_t* Wot  = (ushort_t*)(w + 58720256);    // Wo^T bf16           8,388,608 B
    ushort_t* Qb   = (ushort_t*)(w + 67108864);    // Q roped [BH][L][D'] 33,554,432 B
    ushort_t* Kbf  = (ushort_t*)(w + 100663296);   // K roped [BH][L][D'] 33,554,432 B
    ushort_t* Vt   = (ushort_t*)(w + 134217728);   // V^T    [BH][D][L]  33,554,432 B
    ushort_t* AO   = (ushort_t*)(w + 167772160);   // attn out bf16      33,554,432 B
    float2*   rope = (float2*)(w + 201326592);     // [L][64] cos/sin     1,048,576 B

    cvt_bf16_kernel<<<16384, 256, 0, stream>>>((const float4*)x, (us4*)xb, 4194304);
    transpose_wqkv<<<dim3(96, 32), 256, 0, stream>>>(Wqkv, W1t);
    transpose_bf16<<<dim3(32, 32), 256, 0, stream>>>(Wo, Wot, 2048, 2048);
    rope_table_kernel<<<512, 256, 0, stream>>>(rope);

    // qkv GEMM (256^2 8-phase, single-barrier) + fused rope/reshape epilogue
    gemm256<1><<<768, 512, 0, stream>>>(xb, W1t, 8192, 6144, 2048,
                                        nullptr, Qb, Kbf, Vt, rope);
    // causal flash attention: 8-wave blocks, LDS-shared K/V, permlane pack
    attn_fwd<<<256, 512, 0, stream>>>(Qb, Kbf, Vt, AO);
    // output projection (256^2 8-phase, single-barrier)
    gemm256<0><<<256, 512, 0, stream>>>(AO, Wot, 8192, 2048, 2048,
                                        out, nullptr, nullptr, nullptr, nullptr);
}

// Round 21
// 408.482 us; speedup vs baseline: 1.0130x; 1.0028x over previous
//
#include <hip/hip_runtime.h>
#include <hip/hip_bf16.h>
#include <stdint.h>

typedef unsigned short ushort_t;
typedef __bf16 bf16x8 __attribute__((ext_vector_type(8)));
typedef float    f32x4 __attribute__((ext_vector_type(4)));
typedef float   f32x16 __attribute__((ext_vector_type(16)));
typedef unsigned short us4 __attribute__((ext_vector_type(4)));
typedef unsigned int ui4 __attribute__((ext_vector_type(4)));

#define QK_SCALE 0.12751744f   /* log2(e) / sqrt(128) : folded into Q so softmax uses exp2 */
#define NEG_BIG  -1e30f

#define BARRIER() do { asm volatile("" ::: "memory"); __builtin_amdgcn_s_barrier(); asm volatile("" ::: "memory"); } while (0)
#define VMCNT(N)  asm volatile("s_waitcnt vmcnt(" #N ")" ::: "memory")
#define MFMA16(d, a, b) d = __builtin_amdgcn_mfma_f32_16x16x32_bf16(a, b, d, 0, 0, 0)

__device__ __forceinline__ unsigned short f2bf(float f) {
    union { float f; unsigned int u; } v; v.f = f;
    unsigned int u = v.u;
    return (unsigned short)((u + 0x7FFFu + ((u >> 16) & 1u)) >> 16);  // RNE
}

// HW packed convert: dst.lo = bf16(a), dst.hi = bf16(b)
__device__ __forceinline__ unsigned int pk2bf(float a, float b) {
    unsigned int r;
    asm("v_cvt_pk_bf16_f32 %0, %1, %2" : "=v"(r) : "v"(a), "v"(b));
    return r;
}

// async global->LDS, 16B per lane. LDS dest is wave-uniform base + lane*16.
__device__ __forceinline__ void gload16(const void* g, void* l) {
    __builtin_amdgcn_global_load_lds(
        (__attribute__((address_space(1))) void*)(uintptr_t)g,
        (__attribute__((address_space(3))) void*)(uint32_t)(uintptr_t)l,
        16, 0, 0);
}

// ---------------- prep kernels ----------------

__global__ __launch_bounds__(256) void cvt_bf16_kernel(
    const float4* __restrict__ in, us4* __restrict__ out, int n4) {
    int i = blockIdx.x * 256 + threadIdx.x;
    if (i >= n4) return;
    float4 v = in[i];
    us4 o; o[0] = f2bf(v.x); o[1] = f2bf(v.y); o[2] = f2bf(v.z); o[3] = f2bf(v.w);
    out[i] = o;
}

// generic: in [R][C] fp32 -> out [C][R] bf16
__global__ __launch_bounds__(256) void transpose_bf16(
    const float* __restrict__ in, ushort_t* __restrict__ out, int R, int C) {
    __shared__ float t[64][65];
    int c0 = blockIdx.x * 64, r0 = blockIdx.y * 64;
    int cc = threadIdx.x & 63, rr = threadIdx.x >> 6;
#pragma unroll
    for (int i = 0; i < 16; ++i) {
        int r = i * 4 + rr;
        t[r][cc] = in[(size_t)(r0 + r) * C + c0 + cc];
    }
    __syncthreads();
#pragma unroll
    for (int i = 0; i < 16; ++i) {
        int r = i * 4 + rr;
        out[(size_t)(c0 + r) * R + r0 + cc] = f2bf(t[cc][r]);
    }
}

// Wqkv transpose with Q/K head-dim bit-permutation (R8-verified, QK^T-invariant)
__global__ __launch_bounds__(256) void transpose_wqkv(
    const float* __restrict__ in /*[2048][6144]*/, ushort_t* __restrict__ out /*[6144][2048]*/) {
    __shared__ float t[64][65];
    int c0 = blockIdx.x * 64, r0 = blockIdx.y * 64;
    int cc = threadIdx.x & 63, rr = threadIdx.x >> 6;
    int n = c0 + cc;
    int which = n >> 11;
    int src = n;
    if (which < 2) {
        int h = (n >> 7) & 15, p = n & 127;
        int po = (p & 15) | (((p >> 5) & 3) << 4) | (((p >> 4) & 1) << 6);
        src = (which << 11) + (h << 7) + po;
    }
#pragma unroll
    for (int i = 0; i < 16; ++i) {
        int r = i * 4 + rr;
        t[r][cc] = in[(size_t)(r0 + r) * 6144 + src];
    }
    __syncthreads();
#pragma unroll
    for (int i = 0; i < 16; ++i) {
        int r = i * 4 + rr;
        out[(size_t)(c0 + r) * 2048 + r0 + cc] = f2bf(t[cc][r]);
    }
}

// rope table: [L][64] of (cos, sin)
__global__ __launch_bounds__(256) void rope_table_kernel(float2* __restrict__ rope) {
    int i = blockIdx.x * 256 + threadIdx.x;     // L*64 = 131072 exactly
    int l = i >> 6, j = i & 63;
    float inv = exp2f((float)j * -0.20762050593046f);  // 10000^(-j/64)
    float f = (float)l * inv;
    rope[i] = make_float2(cosf(f), sinf(f));
}

// ---------------- 256x256 8-phase GEMM: single barrier per phase (R16, verified best) ----------------

template <int EPI>
__global__ __launch_bounds__(512, 2)
void gemm256(const ushort_t* __restrict__ A, const ushort_t* __restrict__ Bt,
             int M, int N, int K,
             float* __restrict__ C,
             ushort_t* __restrict__ Qb, ushort_t* __restrict__ Kb,
             ushort_t* __restrict__ Vt, const float2* __restrict__ rope) {
    __shared__ __attribute__((aligned(16))) char lds[131072];

    const int tid  = threadIdx.x;
    const int lane = tid & 63, wid = tid >> 6;
    const int lr = lane & 15, lg = lane >> 4;
    const int wr = wid >> 2, wc = wid & 3;        // wave grid 2(M) x 4(N)

    const int nbn = N >> 8;
    const int nwg = gridDim.x;
    const int bid = blockIdx.x;
    const int wg  = (bid & 7) * (nwg >> 3) + (bid >> 3);   // XCD-contiguous
    const int bm  = wg / nbn, bn = wg % nbn;

    const int srow = tid >> 3;                                   // 0..63
    const int scol = ((tid & 7) << 4) ^ ((srow & 7) << 4);
    const size_t rowK2 = (size_t)K * 2;
    const char* sA0 = (const char*)A + ((size_t)(bm * 256 + srow)) * rowK2 + scol;
    const char* sA1 = sA0 + 128 * rowK2;
    const char* sB0 = (const char*)Bt + ((size_t)(bn * 256 + srow)) * rowK2 + scol;
    const char* sB1 = sB0 + 128 * rowK2;

    auto stg = [&](const char* s, int ch, int kt, int dst) {
        gload16(s + (size_t)(ch * 64) * rowK2 + (size_t)kt * 128, lds + dst + wid * 1024);
    };

    const int xk0 = (lg * 16) ^ ((lr & 7) << 4);
    const int xk1 = (64 + lg * 16) ^ ((lr & 7) << 4);
    const int rowA = wr * 16384 + lr * 128;
    const int rowB = 32768 + (wc >> 1) * 16384 + ((wc & 1) * 64 + lr) * 128;

    auto rdA = [&](int bu, int mi, int kk) -> bf16x8 {
        return *(const bf16x8*)(lds + bu * 65536 + rowA + mi * 2048 + (kk ? xk1 : xk0));
    };
    auto rdB = [&](int bu, int ni, int kk) -> bf16x8 {
        return *(const bf16x8*)(lds + bu * 65536 + rowB + ni * 2048 + (kk ? xk1 : xk0));
    };

    f32x4 acc[8][4];
#pragma unroll
    for (int m = 0; m < 8; ++m)
#pragma unroll
        for (int n = 0; n < 4; ++n) acc[m][n] = (f32x4){0.f, 0.f, 0.f, 0.f};

    bf16x8 aF[4][2], bF[2][2];

#define RD_A(BU, MH) do { _Pragma("unroll") for (int mi = 0; mi < 4; ++mi) { \
        aF[mi][0] = rdA(BU, (MH)*4 + mi, 0); aF[mi][1] = rdA(BU, (MH)*4 + mi, 1); } } while (0)
#define RD_B(BU, NH) do { _Pragma("unroll") for (int ni = 0; ni < 2; ++ni) { \
        bF[ni][0] = rdB(BU, (NH)*2 + ni, 0); bF[ni][1] = rdB(BU, (NH)*2 + ni, 1); } } while (0)
#define QUAD(MH, NH) do { __builtin_amdgcn_s_setprio(1); \
        _Pragma("unroll") for (int kk = 0; kk < 2; ++kk) \
        _Pragma("unroll") for (int mi = 0; mi < 4; ++mi) \
        _Pragma("unroll") for (int ni = 0; ni < 2; ++ni) \
            MFMA16(acc[(MH)*4 + mi][(NH)*2 + ni], aF[mi][kk], bF[ni][kk]); \
        __builtin_amdgcn_s_setprio(0); } while (0)

    // ---- prologue: buf0 <- tile0 (8 chunks); buf1 <- tile1 {A0c1,A1c1,B0c0,B0c1} ----
    stg(sA0, 0, 0, 0);     stg(sA0, 1, 0, 8192);
    stg(sA1, 0, 0, 16384); stg(sA1, 1, 0, 24576);
    stg(sB0, 0, 0, 32768); stg(sB0, 1, 0, 40960);
    stg(sB1, 0, 0, 49152); stg(sB1, 1, 0, 57344);
    stg(sA0, 1, 1, 73728); stg(sA1, 1, 1, 90112);
    stg(sB0, 0, 1, 98304); stg(sB0, 1, 1, 106496);
    VMCNT(4);
    BARRIER();

    const int NIT = K / 128;
    for (int i = 0; i < NIT; ++i) {
        const int to = 2 * i + 1, te2 = 2 * i + 2, to2 = 2 * i + 3;
        const bool g = (i + 1 < NIT);

        // P1
        RD_A(0, 0); RD_B(0, 0);
        stg(sB1, 0, to, 114688); stg(sB1, 1, to, 122880);
        QUAD(0, 0); BARRIER();

        // P2
        RD_A(0, 1);
        stg(sA0, 0, to, 65536); stg(sA1, 0, to, 81920);
        QUAD(1, 0); BARRIER();

        // P3
        RD_B(0, 1);
        if (g) { stg(sA0, 1, te2, 8192); stg(sA1, 1, te2, 24576); }
        QUAD(1, 1); BARRIER();

        // P4 — vmcnt gates buf1 'to' readiness (all waves vmcnt before the shared barrier)
        RD_A(0, 0);
        if (g) { stg(sB0, 0, te2, 32768); stg(sB0, 1, te2, 40960); VMCNT(4); }
        else   { VMCNT(0); }
        QUAD(0, 1); BARRIER();

        // P5
        RD_A(1, 0); RD_B(1, 0);
        if (g) { stg(sB1, 0, te2, 49152); stg(sB1, 1, te2, 57344); }
        QUAD(0, 0); BARRIER();

        // P6
        RD_A(1, 1);
        if (g) { stg(sA0, 0, te2, 0); stg(sA1, 0, te2, 16384); }
        QUAD(1, 0); BARRIER();

        // P7
        RD_B(1, 1);
        if (g) { stg(sA0, 1, to2, 73728); stg(sA1, 1, to2, 90112); }
        QUAD(1, 1); BARRIER();

        // P8 — vmcnt gates buf0 te+2 readiness
        RD_A(1, 0);
        if (g) { stg(sB0, 0, to2, 98304); stg(sB0, 1, to2, 106496); VMCNT(4); }
        QUAD(0, 1); BARRIER();
    }

#undef RD_A
#undef RD_B
#undef QUAD

    if constexpr (EPI == 0) {
#pragma unroll
        for (int m = 0; m < 8; ++m) {
            int gr0 = bm * 256 + wr * 128 + m * 16 + lg * 4;
#pragma unroll
            for (int n = 0; n < 4; ++n) {
                int gc = bn * 256 + wc * 64 + n * 16 + lr;
#pragma unroll
                for (int r = 0; r < 4; ++r)
                    C[(size_t)(gr0 + r) * N + gc] = acc[m][n][r];
            }
        }
    } else {
        const int hc = bn * 2 + (wc >> 1);       // 0..47
        const int which = hc >> 4, h = hc & 15;
#pragma unroll
        for (int m = 0; m < 8; ++m) {
            int gr0 = bm * 256 + wr * 128 + m * 16 + lg * 4;   // b*L + l0
            int b = gr0 >> 11, l0 = gr0 & 2047;
            if (which == 2) {                    // V -> [BH][D][L], d unpermuted
#pragma unroll
                for (int n = 0; n < 4; ++n) {
                    int d = (wc & 1) * 64 + n * 16 + lr;
                    us4 pk;
#pragma unroll
                    for (int r = 0; r < 4; ++r) pk[r] = f2bf(acc[m][n][r]);
                    *(us4*)(Vt + ((size_t)(b * 16 + h) * 128 + d) * 2048 + l0) = pk;
                }
            } else {                             // Q/K: rope on lane-local pairs (np, np+1)
                ushort_t* dst = (which == 0) ? Qb : Kb;
                const float sc = (which == 0) ? QK_SCALE : 1.0f;
#pragma unroll
                for (int np = 0; np < 4; np += 2) {
                    int tbl = ((wc & 1) * 2 + (np >> 1)) * 16 + lr;   // orig dim 0..63
                    int p1 = (wc & 1) * 64 + np * 16 + lr;            // permuted d
#pragma unroll
                    for (int r = 0; r < 4; ++r) {
                        float2 cs = rope[(size_t)(l0 + r) * 64 + tbl];
                        float x1 = acc[m][np][r], x2 = acc[m][np + 1][r];
                        size_t base = ((size_t)(b * 16 + h) * 2048 + (l0 + r)) * 128;
                        dst[base + p1]      = f2bf((x1 * cs.x - x2 * cs.y) * sc);
                        dst[base + p1 + 16] = f2bf((x2 * cs.x + x1 * cs.y) * sc);
                    }
                }
            }
        }
    }
}

// ---------------- causal flash attention: 8-wave LDS-shared K/V, 4-bit XOR swizzle ----------------
// R16 structure; LDS swizzle widened from (row&7)<<4 to (row&15)<<4 on BOTH the staging
// source and all reads (rule-21 involution pairing). Rows are 256B = 16 slots; 3-bit swizzle
// spread a half-wave over only 8 slots (16 acc/bank = 2x the wave64-b128 minimum -> 8.5M
// SQ_LDS_BANK_CONFLICT measured in R20); 4-bit uses all 16 slots (2 lanes/slot = free).
// All read rows satisfy row&15 == q_l&15 (kloc, 32, d0*32 are multiples of 16).

__global__ __attribute__((amdgpu_flat_work_group_size(512, 512), amdgpu_waves_per_eu(2, 2)))
void attn_fwd(const ushort_t* __restrict__ Qb, const ushort_t* __restrict__ Kb,
              const ushort_t* __restrict__ Vt, ushort_t* __restrict__ AO) {
    constexpr int L = 2048;
    __shared__ __attribute__((aligned(16))) char smem[131072];  // [buf][K 32KB | V 32KB]

    const int tid  = threadIdx.x;
    const int lane = tid & 63, wid = tid >> 6;
    const int q_l  = lane & 31;
    const int hi   = lane >> 5;

    const int bid  = blockIdx.x;
    const int hl   = (bid >> 3) & 7;
    const int pr   = bid >> 6;
    const int head = (bid & 7) * 8 + hl;

    const ushort_t* Qh = Qb + (size_t)head * L * 128;
    const char*     KhB = (const char*)(Kb + (size_t)head * L * 128);
    const char*     VhB = (const char*)(Vt + (size_t)head * 128 * L);
    const int b = head >> 4, h = head & 15;

    int rKV[4], cK[4], cV[4];
#pragma unroll
    for (int i = 0; i < 4; ++i) {
        rKV[i] = wid * 16 + i * 4 + (lane >> 4);                  // rows 0..127
        cK[i]  = ((lane & 15) << 4) ^ ((rKV[i] & 15) << 4);       // 4-bit pre-swizzled src col
        cV[i]  = cK[i];
    }
    const int kdst = wid * 4096;
    const int vdst = 32768 + wid * 4096;
    const int xsw  = (q_l & 15) << 4;            // read-side swizzle (row&15)<<4 == (q_l&15)<<4

    for (int ph = 0; ph < 2; ++ph) {
        const int s    = ph ? (7 - pr) : pr;
        const int q0w  = s * 256 + wid * 32;
        const int nch  = 2 * s + 2;            // 128-row chunks

        bf16x8 qf[8];
#pragma unroll
        for (int sb = 0; sb < 8; ++sb)
            qf[sb] = *(const bf16x8*)(Qh + (size_t)(q0w + q_l) * 128 + sb * 16 + hi * 8);

        f32x16 o[4];
#pragma unroll
        for (int d0 = 0; d0 < 4; ++d0) o[d0] = (f32x16)(0.f);
        float m_ = -__builtin_inff(), l_ = 0.f;

        __syncthreads();                        // phase boundary (buffers quiescent)
#pragma unroll
        for (int i = 0; i < 4; ++i) {
            gload16(KhB + (size_t)rKV[i] * 256 + cK[i], smem + kdst + i * 1024);
            gload16(VhB + (size_t)rKV[i] * 4096 + cV[i], smem + vdst + i * 1024);
        }

        for (int c = 0; c < nch; ++c) {
            __syncthreads();                    // stage(c) landed
            const int kb = (c & 1) * 65536;
            const int nb = ((c + 1) & 1) * 65536;
            if (c + 1 < nch) {
                const int kn = 128 * (c + 1);
#pragma unroll
                for (int i = 0; i < 4; ++i) {
                    gload16(KhB + (size_t)(kn + rKV[i]) * 256 + cK[i], smem + nb + kdst + i * 1024);
                    gload16(VhB + (size_t)rKV[i] * 4096 + (size_t)kn * 2 + cV[i], smem + nb + vdst + i * 1024);
                }
            }

#pragma unroll
            for (int sub = 0; sub < 2; ++sub) {
                const int k0 = 128 * c + 64 * sub;
                if (k0 > q0w + 31) continue;
                const bool do1 = (k0 + 32 <= q0w + 31);
                const int kloc = sub * 64;

                f32x16 s0, s1;
                {
                    bf16x8 kf[8];
#pragma unroll
                    for (int sb = 0; sb < 8; ++sb) {
                        int off = kb + (kloc + q_l) * 256 + ((sb * 32 + hi * 16) ^ xsw);
                        kf[sb] = *(const bf16x8*)(smem + off);
                    }
                    f32x16 sA = (f32x16)(0.f), sB = (f32x16)(0.f);
#pragma unroll
                    for (int sb = 0; sb < 8; sb += 2) {
                        sA = __builtin_amdgcn_mfma_f32_32x32x16_bf16(kf[sb],     qf[sb],     sA, 0, 0, 0);
                        sB = __builtin_amdgcn_mfma_f32_32x32x16_bf16(kf[sb + 1], qf[sb + 1], sB, 0, 0, 0);
                    }
                    s0 = sA + sB;
                }
                if (do1) {
                    bf16x8 kf[8];
#pragma unroll
                    for (int sb = 0; sb < 8; ++sb) {
                        int off = kb + (kloc + 32 + q_l) * 256 + ((sb * 32 + hi * 16) ^ xsw);
                        kf[sb] = *(const bf16x8*)(smem + off);
                    }
                    f32x16 sA = (f32x16)(0.f), sB = (f32x16)(0.f);
#pragma unroll
                    for (int sb = 0; sb < 8; sb += 2) {
                        sA = __builtin_amdgcn_mfma_f32_32x32x16_bf16(kf[sb],     qf[sb],     sA, 0, 0, 0);
                        sB = __builtin_amdgcn_mfma_f32_32x32x16_bf16(kf[sb + 1], qf[sb + 1], sB, 0, 0, 0);
                    }
                    s1 = sA + sB;
                }

                if (k0 + 31 > q0w) {
#pragma unroll
                    for (int r = 0; r < 16; ++r) {
                        int crow = (r & 3) + 8 * (r >> 2) + 4 * hi;
                        if (k0 + crow > q0w + q_l) s0[r] = NEG_BIG;
                    }
                }
                if (do1 && (k0 + 63 > q0w)) {
#pragma unroll
                    for (int r = 0; r < 16; ++r) {
                        int crow = (r & 3) + 8 * (r >> 2) + 4 * hi;
                        if (k0 + 32 + crow > q0w + q_l) s1[r] = NEG_BIG;
                    }
                }

                float t8[8];
#pragma unroll
                for (int r = 0; r < 8; ++r) t8[r] = fmaxf(s0[r], s0[r + 8]);
                if (do1)
#pragma unroll
                    for (int r = 0; r < 8; ++r) t8[r] = fmaxf(t8[r], fmaxf(s1[r], s1[r + 8]));
#pragma unroll
                for (int r = 0; r < 4; ++r) t8[r] = fmaxf(t8[r], t8[r + 4]);
                float tmax = fmaxf(fmaxf(t8[0], t8[1]), fmaxf(t8[2], t8[3]));
                tmax = fmaxf(tmax, __shfl_xor(tmax, 32, 64));

                if (!__all(tmax <= m_ + 8.f)) {
                    float mn = fmaxf(m_, tmax);
                    float alpha = exp2f(m_ - mn);
                    m_ = mn;
                    l_ *= alpha;
#pragma unroll
                    for (int d0 = 0; d0 < 4; ++d0)
#pragma unroll
                        for (int r = 0; r < 16; ++r) o[d0][r] *= alpha;
                }

                float rs = 0.f;
#pragma unroll
                for (int r = 0; r < 16; ++r) { s0[r] = exp2f(s0[r] - m_); rs += s0[r]; }
                if (do1)
#pragma unroll
                    for (int r = 0; r < 16; ++r) { s1[r] = exp2f(s1[r] - m_); rs += s1[r]; }
                rs += __shfl_xor(rs, 32, 64);
                l_ += rs;

                // ---- pack P -> bf16 B-frags via cvt_pk + permlane32_swap (T12) ----
                bf16x8 pfA[2], pfB[2];
                {
                    unsigned int pk[8];
#pragma unroll
                    for (int i = 0; i < 8; ++i) pk[i] = pk2bf(s0[2 * i], s0[2 * i + 1]);
#pragma unroll
                    for (int ks = 0; ks < 2; ++ks) {
                        unsigned int a0 = pk[ks * 4 + 0], b0 = pk[ks * 4 + 2];
                        unsigned int a1 = pk[ks * 4 + 1], b1 = pk[ks * 4 + 3];
                        asm("v_permlane32_swap_b32 %0, %1" : "+v"(a0), "+v"(b0));
                        asm("v_permlane32_swap_b32 %0, %1" : "+v"(a1), "+v"(b1));
                        ui4 dw; dw[0] = a0; dw[1] = a1; dw[2] = b0; dw[3] = b1;
                        pfA[ks] = __builtin_bit_cast(bf16x8, dw);
                    }
                }
                if (do1) {
                    unsigned int pk[8];
#pragma unroll
                    for (int i = 0; i < 8; ++i) pk[i] = pk2bf(s1[2 * i], s1[2 * i + 1]);
#pragma unroll
                    for (int ks = 0; ks < 2; ++ks) {
                        unsigned int a0 = pk[ks * 4 + 0], b0 = pk[ks * 4 + 2];
                        unsigned int a1 = pk[ks * 4 + 1], b1 = pk[ks * 4 + 3];
                        asm("v_permlane32_swap_b32 %0, %1" : "+v"(a0), "+v"(b0));
                        asm("v_permlane32_swap_b32 %0, %1" : "+v"(a1), "+v"(b1));
                        ui4 dw; dw[0] = a0; dw[1] = a1; dw[2] = b0; dw[3] = b1;
                        pfB[ks] = __builtin_bit_cast(bf16x8, dw);
                    }
                }

                const int vb = kb + 32768;
#pragma unroll
                for (int d0 = 0; d0 < 4; ++d0) {
                    int d = d0 * 32 + q_l;
#pragma unroll
                    for (int ks = 0; ks < 2; ++ks) {
                        int off = vb + d * 256 + ((sub * 128 + ks * 32 + hi * 16) ^ xsw);
                        bf16x8 vf = *(const bf16x8*)(smem + off);
                        o[d0] = __builtin_amdgcn_mfma_f32_32x32x16_bf16(vf, pfA[ks], o[d0], 0, 0, 0);
                    }
                    if (do1) {
#pragma unroll
                        for (int ks = 0; ks < 2; ++ks) {
                            int off = vb + d * 256 + ((sub * 128 + (2 + ks) * 32 + hi * 16) ^ xsw);
                            bf16x8 vf = *(const bf16x8*)(smem + off);
                            o[d0] = __builtin_amdgcn_mfma_f32_32x32x16_bf16(vf, pfB[ks], o[d0], 0, 0, 0);
                        }
                    }
                }
            }
        }

        // ---- epilogue ----
        const float inv = 1.f / l_;
        const size_t rowbase = ((size_t)(b * 2048 + q0w + q_l)) * 2048 + h * 128;
#pragma unroll
        for (int d0 = 0; d0 < 4; ++d0)
#pragma unroll
            for (int g = 0; g < 4; ++g) {
                us4 v;
#pragma unroll
                for (int r = 0; r < 4; ++r) v[r] = f2bf(o[d0][g * 4 + r] * inv);
                *(us4*)(AO + rowbase + d0 * 32 + g * 8 + hi * 4) = v;
            }
    }
}

// ---------------- launcher ----------------

extern "C" void kernel_launch(void* const* d_in, const int* in_sizes, int n_in,
                              void* d_out, int out_size, void* d_ws, size_t ws_size,
                              hipStream_t stream) {
    const float* x    = (const float*)d_in[0];   // [4,2048,2048]
    const float* Wqkv = (const float*)d_in[1];   // [2048,6144]
    const float* Wo   = (const float*)d_in[2];   // [2048,2048]
    float* out = (float*)d_out;                  // [4,2048,2048] fp32

    char* w = (char*)d_ws;
    ushort_t* xb   = (ushort_t*)(w);               // x bf16             33,554,432 B
    ushort_t* W1t  = (ushort_t*)(w + 33554432);    // Wqkv^T bf16 (QK-permuted) 25,165,824 B
    ushort_t* Wot  = (ushort_t*)(w + 58720256);    // Wo^T bf16           8,388,608 B
    ushort_t* Qb   = (ushort_t*)(w + 67108864);    // Q roped [BH][L][D'] 33,554,432 B
    ushort_t* Kbf  = (ushort_t*)(w + 100663296);   // K roped [BH][L][D'] 33,554,432 B
    ushort_t* Vt   = (ushort_t*)(w + 134217728);   // V^T    [BH][D][L]  33,554,432 B
    ushort_t* AO   = (ushort_t*)(w + 167772160);   // attn out bf16      33,554,432 B
    float2*   rope = (float2*)(w + 201326592);     // [L][64] cos/sin     1,048,576 B

    cvt_bf16_kernel<<<16384, 256, 0, stream>>>((const float4*)x, (us4*)xb, 4194304);
    transpose_wqkv<<<dim3(96, 32), 256, 0, stream>>>(Wqkv, W1t);
    transpose_bf16<<<dim3(32, 32), 256, 0, stream>>>(Wo, Wot, 2048, 2048);
    rope_table_kernel<<<512, 256, 0, stream>>>(rope);

    // qkv GEMM (256^2 8-phase, single-barrier) + fused rope/reshape epilogue
    gemm256<1><<<768, 512, 0, stream>>>(xb, W1t, 8192, 6144, 2048,
                                        nullptr, Qb, Kbf, Vt, rope);
    // causal flash attention: 8-wave blocks, LDS-shared K/V, 4-bit swizzle
    attn_fwd<<<256, 512, 0, stream>>>(Qb, Kbf, Vt, AO);
    // output projection (256^2 8-phase, single-barrier)
    gemm256<0><<<256, 512, 0, stream>>>(AO, Wot, 8192, 2048, 2048,
                                        out, nullptr, nullptr, nullptr, nullptr);
}